// Round 3
// baseline (542.309 us; speedup 1.0000x reference)
//
#include <hip/hip_runtime.h>
#include <hip/hip_bf16.h>
#include <math.h>

#define TOKENS 8192
#define IN_F   4096
#define OUT_F  4096
#define LR     16

typedef __bf16 bf16_t;
typedef __attribute__((ext_vector_type(8)))  __bf16 bf16x8;
typedef __attribute__((ext_vector_type(4)))  __bf16 bf16x4;
typedef __attribute__((ext_vector_type(4)))  float  floatx4;
typedef __attribute__((ext_vector_type(16))) float  floatx16;

#define GL2LDS(gp, lp) \
    __builtin_amdgcn_global_load_lds((const __attribute__((address_space(1))) unsigned int*)(gp), \
                                     (__attribute__((address_space(3))) unsigned int*)(lp), 16, 0, 0)

// ---------------- kernel 1: P = A A^T (16x16), Q = B^T B (16x16) ----------------
__global__ void pq_kernel(const float* __restrict__ A, const float* __restrict__ B,
                          float* __restrict__ P, float* __restrict__ Q) {
    __shared__ float red[256];
    const int b = blockIdx.x, t = threadIdx.x;
    float s = 0.f;
    if (b < 256) {
        const int i = b >> 4, j = b & 15;
        const float* ai = A + (size_t)i * IN_F;
        const float* aj = A + (size_t)j * IN_F;
        for (int k = t; k < IN_F; k += 256) s += ai[k] * aj[k];
    } else {
        const int i = (b - 256) >> 4, j = (b - 256) & 15;
        for (int k = t; k < OUT_F; k += 256) s += B[k * LR + i] * B[k * LR + j];
    }
    red[t] = s; __syncthreads();
    for (int off = 128; off > 0; off >>= 1) {
        if (t < off) red[t] += red[t + off];
        __syncthreads();
    }
    if (t == 0) {
        if (b < 256) P[b] = red[0];
        else         Q[b - 256] = red[0];
    }
}

// ---------------- kernel 2: rank-space Newton-Schulz (fp64, 16x16) ----------------
__global__ void ns_kernel(const float* __restrict__ P, const float* __restrict__ Q,
                          float* __restrict__ Sc) {
    __shared__ double Ps[256], Qs[256], Ss[256], Ys[256], Zs[256], Ts[256], Us[256], Vs[256];
    __shared__ double Tr[256];
    __shared__ double alpha_s, inv_n;
    const int t = threadIdx.x, i = t >> 4, j = t & 15;
    Ps[t] = P[t]; Qs[t] = Q[t];
    __syncthreads();
    // tr(P Q) via parallel 256-way product + tree reduce (was thread-0 serial)
    Tr[t] = Ps[t] * Qs[(t & 15) * 16 + (t >> 4)];
    __syncthreads();
    for (int off = 128; off > 0; off >>= 1) {
        if (t < off) Tr[t] += Tr[t + off];
        __syncthreads();
    }
    if (t == 0) {
        const double al = sqrt(Tr[0]);       // ||G||_F = sqrt(tr(P Q))
        alpha_s = al;
        inv_n   = 1.0 / (al + 1e-7);
    }
    __syncthreads();
    Ss[t] = (i == j) ? inv_n : 0.0;          // S_0 = I / (||G|| + eps)
    __syncthreads();
    const double ca = 3.4445, cb = -4.775, cc = 2.0315;
    for (int step = 0; step < 5; ++step) {
        double s;
        s = 0; for (int q = 0; q < 16; ++q) s += Ss[i*16+q] * Ps[q*16+j]; Ys[t] = s; __syncthreads(); // Y = S P
        s = 0; for (int q = 0; q < 16; ++q) s += Ys[i*16+q] * Ss[j*16+q]; Zs[t] = s; __syncthreads(); // Z = Y S^T
        s = 0; for (int q = 0; q < 16; ++q) s += Zs[i*16+q] * Qs[q*16+j]; Ts[t] = s; __syncthreads(); // T = Z Q
        s = 0; for (int q = 0; q < 16; ++q) s += Ts[i*16+q] * Ss[q*16+j]; Us[t] = s; __syncthreads(); // U = T S
        s = 0; for (int q = 0; q < 16; ++q) s += Ts[i*16+q] * Us[q*16+j]; Vs[t] = s; __syncthreads(); // V = T U
        Ss[t] = ca * Ss[t] + cb * Us[t] + cc * Vs[t];
        __syncthreads();
    }
    Sc[t] = (float)(alpha_s * Ss[t]);
}

// ---------------- kernel 3 (fused): x->bf16 convert + W_eff = W + (B Sc) A  ------
// sca_kernel folded in: B@(Sc@A) == (B@Sc)@A; each weff block computes its own
// 4x16 slab of BSc = B@Sc in LDS (1024 FMA, trivial), then streams lora_A rows.
// Removes one launch and the ScA global round-trip.
__global__ void prep_kernel(const float* __restrict__ x, bf16_t* __restrict__ Xb,
                            const float* __restrict__ W, const float* __restrict__ Bm,
                            const float* __restrict__ Sc, const float* __restrict__ Al,
                            bf16_t* __restrict__ Wb) {
    const int b = blockIdx.x, t = threadIdx.x;
    if (b < 32768) {
        const int idx = b * 256 + t;                  // float4 index
        const float4 u = ((const float4*)x)[idx];
        bf16x4 v;
        v[0] = (__bf16)u.x; v[1] = (__bf16)u.y; v[2] = (__bf16)u.z; v[3] = (__bf16)u.w;
        ((bf16x4*)Xb)[idx] = v;
        return;
    }
    __shared__ float bsc[64];                 // BSc rows o0..o0+3  [4][16]
    const int bb = b - 32768;
    const int o0 = (bb >> 2) * 4;             // 4 output rows per block
    if (t < 64) {
        const int r = t >> 4, sI = t & 15;
        float s = 0.f;
        #pragma unroll
        for (int q = 0; q < 16; ++q) s += Bm[(o0 + r) * LR + q] * Sc[q * 16 + sI];
        bsc[t] = s;
    }
    __syncthreads();
    const int i = (bb & 3) * 1024 + t * 4;    // 4 consecutive cols per thread
    float4 acc[4];
    #pragma unroll
    for (int r = 0; r < 4; ++r) acc[r] = *(const float4*)&W[(size_t)(o0 + r) * IN_F + i];
    #pragma unroll
    for (int q = 0; q < LR; ++q) {
        const float4 av = *(const float4*)&Al[(size_t)q * IN_F + i];
        #pragma unroll
        for (int r = 0; r < 4; ++r) {
            const float bq = bsc[r * 16 + q];
            acc[r].x += bq * av.x; acc[r].y += bq * av.y;
            acc[r].z += bq * av.z; acc[r].w += bq * av.w;
        }
    }
    #pragma unroll
    for (int r = 0; r < 4; ++r) {
        bf16x4 v;
        v[0] = (__bf16)acc[r].x; v[1] = (__bf16)acc[r].y;
        v[2] = (__bf16)acc[r].z; v[3] = (__bf16)acc[r].w;
        *(bf16x4*)&Wb[(size_t)(o0 + r) * IN_F + i] = v;
    }
}

// ---------------- kernel 4: C = Xb @ Wb^T + bias  --------------------------------
// Round-6: same 8-phase counted-vmcnt schedule as round-5 (verified: conflicts=0,
// MfmaUtil 53% of shape-peak), but inner op switched 16x16x32 -> 32x32x16
// (m119: 2495 vs 2176 TF stream ceiling, +15%; half the MFMA instructions).
//   256x256 tile, BK=64 as 2 K-half units of 32; 8 waves (2M x 4N), 128x64/wave;
//   per phase: 8x mfma_32x32x16, acc[4][2] floatx16 = 128 VGPR.
// LDS = 2 dbuf x 2 K-half x (A,B) x [256][32] units of 16 KB = 128 KB, 1 blk/CU.
// Phase p in {(kh0,ks0),(kh0,ks1),(kh1,ks0),(kh1,ks1)}: {4 A + 2 B ds_read_b128
//   + one 16KB half-unit prefetch} -> bar -> setprio(1) + 8 MFMA -> [vmcnt] -> bar.
// vmcnt(4) at P1/P3 trailing edges only (counted, never 0 until last tile) --
// same issue-slot/wait-point proof as round-5.
// T2 swizzle: unit elem = r*32 + pc*8 + e, pc = c ^ ((r>>1)&3).  32x32 frag read
// (row=lane&31, chunk=ks*2+kg): bank-group = 4(r&1) | pc hits all 8 groups
// exactly 8x per 64-lane b128 -> uniform, conflict-free (verified: 0 conflicts).
// gl2lds dest LINEAR; global SOURCE inverse-swizzled (both-sides rule m231).
#define GNT 64              // K-tiles of 64

#define FENCE asm volatile("" ::: "memory")
#define BAR   do { __builtin_amdgcn_s_barrier(); FENCE; } while (0)
#define PRIO1 __builtin_amdgcn_s_setprio(1)
#define PRIO0 __builtin_amdgcn_s_setprio(0)

// stage one 16KB half-unit: 512 threads x 2 chunks of 16B
#define STG(ubase, srcp, koff) do { \
    GL2LDS((srcp) + (koff), &lds[(ubase) + t * 8]); \
    GL2LDS((srcp) + (size_t)128 * IN_F + (koff), &lds[(ubase) + 4096 + t * 8]); } while (0)

// per-phase fragment reads: unit (KH*2+D), k-sub slot SL
#define PH(KH, D, SL) do { \
    af[0] = *(const bf16x8*)&lds[aRd + ((KH)*2+(D))*8192 + 0*1024 + (SL)]; \
    af[1] = *(const bf16x8*)&lds[aRd + ((KH)*2+(D))*8192 + 1*1024 + (SL)]; \
    af[2] = *(const bf16x8*)&lds[aRd + ((KH)*2+(D))*8192 + 2*1024 + (SL)]; \
    af[3] = *(const bf16x8*)&lds[aRd + ((KH)*2+(D))*8192 + 3*1024 + (SL)]; \
    bfv[0] = *(const bf16x8*)&lds[bRd + ((KH)*2+(D))*8192 + 0*1024 + (SL)]; \
    bfv[1] = *(const bf16x8*)&lds[bRd + ((KH)*2+(D))*8192 + 1*1024 + (SL)]; } while (0)

#define MFMA8() do { \
    _Pragma("unroll") \
    for (int _i = 0; _i < 4; ++_i) { \
        acc[_i][0] = __builtin_amdgcn_mfma_f32_32x32x16_bf16(af[_i], bfv[0], acc[_i][0], 0, 0, 0); \
        acc[_i][1] = __builtin_amdgcn_mfma_f32_32x32x16_bf16(af[_i], bfv[1], acc[_i][1], 0, 0, 0); \
    } } while (0)

// one K-tile = 4 phases.  D = dbuf of this tile, DN = 1-D, KTN = tile staged.
#define KTILE(D, DN, KTN, DO_STAGE, DO_VM_END) do { \
    bf16x8 af[4]; bf16x8 bfv[2]; \
    PH(0, D, sl0); \
    if (DO_STAGE) STG(32768 + (DN)*8192, sB, (size_t)(KTN)*64); \
    BAR; PRIO1; MFMA8(); PRIO0; BAR; \
    PH(0, D, sl1); \
    if (DO_STAGE) STG((DN)*8192, sA, (size_t)(KTN)*64); \
    BAR; PRIO1; MFMA8(); PRIO0; \
    if (DO_STAGE) asm volatile("s_waitcnt vmcnt(4)" ::: "memory"); \
    else          asm volatile("s_waitcnt vmcnt(0)" ::: "memory"); \
    BAR; \
    PH(1, D, sl0); \
    if (DO_STAGE) STG(32768 + (2+(DN))*8192, sB, (size_t)(KTN)*64 + 32); \
    BAR; PRIO1; MFMA8(); PRIO0; BAR; \
    PH(1, D, sl1); \
    if (DO_STAGE) STG((2+(DN))*8192, sA, (size_t)(KTN)*64 + 32); \
    BAR; PRIO1; MFMA8(); PRIO0; \
    if (DO_VM_END) asm volatile("s_waitcnt vmcnt(4)" ::: "memory"); \
    BAR; \
} while (0)

__global__ __launch_bounds__(512, 2) void gemm_kernel(
        const bf16_t* __restrict__ Xb, const bf16_t* __restrict__ Wb,
        const float* __restrict__ bias, float* __restrict__ out) {
    __shared__ bf16_t lds[65536];   // 128 KB: A units [4][8192], then B units [4][8192]
    const int t = threadIdx.x;
    const int lane = t & 63, wv = t >> 6;
    const int wm = wv & 1, wn = wv >> 1;          // 2x4 wave grid, 128x64 per wave
    const int ln = lane & 31, kg = lane >> 5;     // 32x32 frag row/col, k-half-of-16

    // T1: bijective XCD swizzle (512 blocks % 8 == 0); XCD r owns nt {2r,2r+1}
    const int bid = blockIdx.x;
    const int swz = (bid & 7) * 64 + (bid >> 3);
    const int mt = swz & 31, nt = swz >> 5;       // 32 x 16 tiles
    const int m0 = mt * 256, n0 = nt * 256;

    // ds_read bases.  rx = (r>>1)&3 depends only on ln (mf*32, nf*32, wm*128,
    // wn*64 are multiples of 4 rows after >>1) -> frag offsets fold to imms.
    const int rx  = (ln >> 1) & 3;
    const int sl0 = ((kg       ^ rx) << 3);       // ks0 chunk = kg
    const int sl1 = (((2 | kg) ^ rx) << 3);       // ks1 chunk = 2|kg
    const int aRd = (wm * 128 + ln) * 32;
    const int bRd = 32768 + (wn * 64 + ln) * 32;

    // staging source (inverse-swizzled): chunk g = j*512+t -> row g>>2, phys
    // chunk g&3 holds logical chunk (g&3)^((g>>3)&3)  (j-independent).
    const int cS = (t & 3) ^ ((t >> 3) & 3);
    const int rS = t >> 2;
    const bf16_t* sA = Xb + (size_t)(m0 + rS) * IN_F + cS * 8;
    const bf16_t* sB = Wb + (size_t)(n0 + rS) * IN_F + cS * 8;

    floatx16 acc[4][2];
    #pragma unroll
    for (int i = 0; i < 4; ++i) {
        acc[i][0] = (floatx16)(0.0f);
        acc[i][1] = (floatx16)(0.0f);
    }

    // prologue: B-kh0(0), A-kh0(0), B-kh1(0), A-kh1(0); wait first two units
    STG(32768 + 0 * 8192, sB, 0);
    STG(0 * 8192,         sA, 0);
    STG(32768 + 2 * 8192, sB, 32);
    STG(2 * 8192,         sA, 32);
    asm volatile("s_waitcnt vmcnt(4)" ::: "memory");
    BAR;

    for (int kt2 = 0; kt2 < GNT / 2 - 1; ++kt2) {
        const int kt = kt2 * 2;
        KTILE(0, 1, kt + 1, true, true);
        KTILE(1, 0, kt + 2, true, true);
    }
    KTILE(0, 1, GNT - 1, true, true);
    KTILE(1, 0, 0, false, false);

    // C/D layout 32x32x16 (m74/m101): col = lane&31, row = (rg&3)+8*(rg>>2)+4*kg
    const int colb = n0 + wn * 64 + ln;
    const int rowb = m0 + wm * 128 + 4 * kg;
    const float bv0 = bias[colb];
    const float bv1 = bias[colb + 32];
    #pragma unroll
    for (int mf = 0; mf < 4; ++mf) {
        #pragma unroll
        for (int rg = 0; rg < 16; ++rg) {
            const int row = rowb + mf * 32 + (rg & 3) + 8 * (rg >> 2);
            out[(size_t)row * OUT_F + colb]      = acc[mf][0][rg] + bv0;
            out[(size_t)row * OUT_F + colb + 32] = acc[mf][1][rg] + bv1;
        }
    }
}

extern "C" void kernel_launch(void* const* d_in, const int* in_sizes, int n_in,
                              void* d_out, int out_size, void* d_ws, size_t ws_size,
                              hipStream_t stream) {
    const float* x    = (const float*)d_in[0];
    const float* W    = (const float*)d_in[1];
    const float* bias = (const float*)d_in[2];
    const float* lA_  = (const float*)d_in[3];
    const float* lB_  = (const float*)d_in[4];
    float* out = (float*)d_out;

    // workspace layout (~101 MB)
    char* ws = (char*)d_ws;
    bf16_t* Xb  = (bf16_t*)ws;                               // 8192*4096*2 = 67108864
    bf16_t* Wb  = (bf16_t*)(ws + 67108864);                  // 4096*4096*2 = 33554432
    float*  P   = (float*)(ws + 100925440);                  // 256 floats
    float*  Q   = P + 256;
    float*  Sc  = Q + 256;

    pq_kernel  <<<512, 256, 0, stream>>>(lA_, lB_, P, Q);
    ns_kernel  <<<1, 256, 0, stream>>>(P, Q, Sc);
    prep_kernel<<<36864, 256, 0, stream>>>(x, Xb, W, lB_, Sc, lA_, Wb);
    gemm_kernel<<<512, 512, 0, stream>>>(Xb, Wb, bias, out);
}

// Round 4
// 541.809 us; speedup vs baseline: 1.0009x; 1.0009x over previous
//
#include <hip/hip_runtime.h>
#include <hip/hip_bf16.h>
#include <math.h>

#define TOKENS 8192
#define IN_F   4096
#define OUT_F  4096
#define LR     16

typedef __bf16 bf16_t;
typedef __attribute__((ext_vector_type(8)))  __bf16 bf16x8;
typedef __attribute__((ext_vector_type(4)))  __bf16 bf16x4;
typedef __attribute__((ext_vector_type(4)))  float  floatx4;
typedef __attribute__((ext_vector_type(16))) float  floatx16;

#define GL2LDS(gp, lp) \
    __builtin_amdgcn_global_load_lds((const __attribute__((address_space(1))) unsigned int*)(gp), \
                                     (__attribute__((address_space(3))) unsigned int*)(lp), 16, 0, 0)

// ---------------- kernel 1: P = A A^T (16x16), Q = B^T B (16x16) ----------------
__global__ void pq_kernel(const float* __restrict__ A, const float* __restrict__ B,
                          float* __restrict__ P, float* __restrict__ Q) {
    __shared__ float red[256];
    const int b = blockIdx.x, t = threadIdx.x;
    float s = 0.f;
    if (b < 256) {
        const int i = b >> 4, j = b & 15;
        const float* ai = A + (size_t)i * IN_F;
        const float* aj = A + (size_t)j * IN_F;
        for (int k = t; k < IN_F; k += 256) s += ai[k] * aj[k];
    } else {
        const int i = (b - 256) >> 4, j = (b - 256) & 15;
        for (int k = t; k < OUT_F; k += 256) s += B[k * LR + i] * B[k * LR + j];
    }
    red[t] = s; __syncthreads();
    for (int off = 128; off > 0; off >>= 1) {
        if (t < off) red[t] += red[t + off];
        __syncthreads();
    }
    if (t == 0) {
        if (b < 256) P[b] = red[0];
        else         Q[b - 256] = red[0];
    }
}

// ---------------- kernel 2: rank-space Newton-Schulz (fp64, 16x16) ----------------
__global__ void ns_kernel(const float* __restrict__ P, const float* __restrict__ Q,
                          float* __restrict__ Sc) {
    __shared__ double Ps[256], Qs[256], Ss[256], Ys[256], Zs[256], Ts[256], Us[256], Vs[256];
    __shared__ double Tr[256];
    __shared__ double alpha_s, inv_n;
    const int t = threadIdx.x, i = t >> 4, j = t & 15;
    Ps[t] = P[t]; Qs[t] = Q[t];
    __syncthreads();
    // tr(P Q) via parallel 256-way product + tree reduce
    Tr[t] = Ps[t] * Qs[(t & 15) * 16 + (t >> 4)];
    __syncthreads();
    for (int off = 128; off > 0; off >>= 1) {
        if (t < off) Tr[t] += Tr[t + off];
        __syncthreads();
    }
    if (t == 0) {
        const double al = sqrt(Tr[0]);       // ||G||_F = sqrt(tr(P Q))
        alpha_s = al;
        inv_n   = 1.0 / (al + 1e-7);
    }
    __syncthreads();
    Ss[t] = (i == j) ? inv_n : 0.0;          // S_0 = I / (||G|| + eps)
    __syncthreads();
    const double ca = 3.4445, cb = -4.775, cc = 2.0315;
    for (int step = 0; step < 5; ++step) {
        double s;
        s = 0; for (int q = 0; q < 16; ++q) s += Ss[i*16+q] * Ps[q*16+j]; Ys[t] = s; __syncthreads(); // Y = S P
        s = 0; for (int q = 0; q < 16; ++q) s += Ys[i*16+q] * Ss[j*16+q]; Zs[t] = s; __syncthreads(); // Z = Y S^T
        s = 0; for (int q = 0; q < 16; ++q) s += Zs[i*16+q] * Qs[q*16+j]; Ts[t] = s; __syncthreads(); // T = Z Q
        s = 0; for (int q = 0; q < 16; ++q) s += Ts[i*16+q] * Ss[q*16+j]; Us[t] = s; __syncthreads(); // U = T S
        s = 0; for (int q = 0; q < 16; ++q) s += Ts[i*16+q] * Us[q*16+j]; Vs[t] = s; __syncthreads(); // V = T U
        Ss[t] = ca * Ss[t] + cb * Us[t] + cc * Vs[t];
        __syncthreads();
    }
    Sc[t] = (float)(alpha_s * Ss[t]);
}

// ---------------- kernel 3 (fused): x->bf16 convert + W_eff = W + (B Sc) A  ------
__global__ void prep_kernel(const float* __restrict__ x, bf16_t* __restrict__ Xb,
                            const float* __restrict__ W, const float* __restrict__ Bm,
                            const float* __restrict__ Sc, const float* __restrict__ Al,
                            bf16_t* __restrict__ Wb) {
    const int b = blockIdx.x, t = threadIdx.x;
    if (b < 32768) {
        const int idx = b * 256 + t;                  // float4 index
        const float4 u = ((const float4*)x)[idx];
        bf16x4 v;
        v[0] = (__bf16)u.x; v[1] = (__bf16)u.y; v[2] = (__bf16)u.z; v[3] = (__bf16)u.w;
        ((bf16x4*)Xb)[idx] = v;
        return;
    }
    __shared__ float bsc[64];                 // BSc rows o0..o0+3  [4][16]
    const int bb = b - 32768;
    const int o0 = (bb >> 2) * 4;             // 4 output rows per block
    if (t < 64) {
        const int r = t >> 4, sI = t & 15;
        float s = 0.f;
        #pragma unroll
        for (int q = 0; q < 16; ++q) s += Bm[(o0 + r) * LR + q] * Sc[q * 16 + sI];
        bsc[t] = s;
    }
    __syncthreads();
    const int i = (bb & 3) * 1024 + t * 4;    // 4 consecutive cols per thread
    float4 acc[4];
    #pragma unroll
    for (int r = 0; r < 4; ++r) acc[r] = *(const float4*)&W[(size_t)(o0 + r) * IN_F + i];
    #pragma unroll
    for (int q = 0; q < LR; ++q) {
        const float4 av = *(const float4*)&Al[(size_t)q * IN_F + i];
        #pragma unroll
        for (int r = 0; r < 4; ++r) {
            const float bq = bsc[r * 16 + q];
            acc[r].x += bq * av.x; acc[r].y += bq * av.y;
            acc[r].z += bq * av.z; acc[r].w += bq * av.w;
        }
    }
    #pragma unroll
    for (int r = 0; r < 4; ++r) {
        bf16x4 v;
        v[0] = (__bf16)acc[r].x; v[1] = (__bf16)acc[r].y;
        v[2] = (__bf16)acc[r].z; v[3] = (__bf16)acc[r].w;
        *(bf16x4*)&Wb[(size_t)(o0 + r) * IN_F + i] = v;
    }
}

// ---------------- kernel 4: C = Xb @ Wb^T + bias  --------------------------------
// Round-7: 32x32x16 MFMA + 8-phase counted-vmcnt schedule (round-3), with the
// LDS permutation REBUILT so every 64-lane ds_read_b128 reproduces round-2's
// HW-PROVEN conflict-free physical pattern (measured 0 conflicts vs 4 extra
// cyc/read for the round-3 xor layout).
//
// Unit = [256 rows][32 k] bf16 = 1024 chunks of 16 B, grouped in 1-KB SLABS:
//   slab(r,c)   = (r>>5)*2 + (c>>1)                 (16 slabs/unit)
//   within slab: fl = r&15, q = ((c&1)<<1) | ((r>>4)&1)
//   chunk_in_slab = fl*4 + (q ^ ((fl>>1)&3))        (bijective)
// A 32x32 frag read (r = R0+ln, c = 2*ks+kg; ln=lane&31, kg=lane>>5) then has
// per-lane chunk T(l) = (l&15)*4 + ((l>>4) ^ (((l&15)>>1)&3)) over ONE slab --
// byte-identical to round-2's measured-zero pattern (q folds to lane>>4).
// gl2lds dest stays LINEAR; global SOURCE is the inverse permutation.
//
// Schedule (unchanged, verified round-2/3): per phase {4 A + 2 B ds_read_b128
// + one 16KB half-unit prefetch} -> bar -> setprio(1)+8 MFMA -> [vmcnt(4)] -> bar;
// counted vmcnt never drains to 0 until the last K-tile.
#define GNT 64              // K-tiles of 64

#define FENCE asm volatile("" ::: "memory")
#define BAR   do { __builtin_amdgcn_s_barrier(); FENCE; } while (0)
#define PRIO1 __builtin_amdgcn_s_setprio(1)
#define PRIO0 __builtin_amdgcn_s_setprio(0)

// stage one 16KB half-unit: 512 threads x 2 chunks of 16B (rows +0 / +128)
#define STG(ubase, srcp, koff) do { \
    GL2LDS((srcp) + (koff), &lds[(ubase) + t * 8]); \
    GL2LDS((srcp) + (size_t)128 * IN_F + (koff), &lds[(ubase) + 4096 + t * 8]); } while (0)

// per-phase fragment reads: unit (KH*2+D), k-sub-slab KS in {0,1}
#define PH(KH, D, KS) do { \
    af[0] = *(const bf16x8*)&lds[aRd + ((KH)*2+(D))*8192 + 0*1024 + (KS)*512]; \
    af[1] = *(const bf16x8*)&lds[aRd + ((KH)*2+(D))*8192 + 1*1024 + (KS)*512]; \
    af[2] = *(const bf16x8*)&lds[aRd + ((KH)*2+(D))*8192 + 2*1024 + (KS)*512]; \
    af[3] = *(const bf16x8*)&lds[aRd + ((KH)*2+(D))*8192 + 3*1024 + (KS)*512]; \
    bfv[0] = *(const bf16x8*)&lds[bRd + ((KH)*2+(D))*8192 + 0*1024 + (KS)*512]; \
    bfv[1] = *(const bf16x8*)&lds[bRd + ((KH)*2+(D))*8192 + 1*1024 + (KS)*512]; } while (0)

#define MFMA8() do { \
    _Pragma("unroll") \
    for (int _i = 0; _i < 4; ++_i) { \
        acc[_i][0] = __builtin_amdgcn_mfma_f32_32x32x16_bf16(af[_i], bfv[0], acc[_i][0], 0, 0, 0); \
        acc[_i][1] = __builtin_amdgcn_mfma_f32_32x32x16_bf16(af[_i], bfv[1], acc[_i][1], 0, 0, 0); \
    } } while (0)

// one K-tile = 4 phases.  D = dbuf of this tile, DN = 1-D, KTN = tile staged.
#define KTILE(D, DN, KTN, DO_STAGE, DO_VM_END) do { \
    bf16x8 af[4]; bf16x8 bfv[2]; \
    PH(0, D, 0); \
    if (DO_STAGE) STG(32768 + (DN)*8192, sB, (size_t)(KTN)*64); \
    BAR; PRIO1; MFMA8(); PRIO0; BAR; \
    PH(0, D, 1); \
    if (DO_STAGE) STG((DN)*8192, sA, (size_t)(KTN)*64); \
    BAR; PRIO1; MFMA8(); PRIO0; \
    if (DO_STAGE) asm volatile("s_waitcnt vmcnt(4)" ::: "memory"); \
    else          asm volatile("s_waitcnt vmcnt(0)" ::: "memory"); \
    BAR; \
    PH(1, D, 0); \
    if (DO_STAGE) STG(32768 + (2+(DN))*8192, sB, (size_t)(KTN)*64 + 32); \
    BAR; PRIO1; MFMA8(); PRIO0; BAR; \
    PH(1, D, 1); \
    if (DO_STAGE) STG((2+(DN))*8192, sA, (size_t)(KTN)*64 + 32); \
    BAR; PRIO1; MFMA8(); PRIO0; \
    if (DO_VM_END) asm volatile("s_waitcnt vmcnt(4)" ::: "memory"); \
    BAR; \
} while (0)

__global__ __launch_bounds__(512, 2) void gemm_kernel(
        const bf16_t* __restrict__ Xb, const bf16_t* __restrict__ Wb,
        const float* __restrict__ bias, float* __restrict__ out) {
    __shared__ bf16_t lds[65536];   // 128 KB: A units [4][8192], then B units [4][8192]
    const int t = threadIdx.x;
    const int lane = t & 63, wv = t >> 6;
    const int wm = wv & 1, wn = wv >> 1;          // 2x4 wave grid, 128x64 per wave
    const int ln = lane & 31, kg = lane >> 5;     // 32x32 frag row, k-half-of-16

    // T1: bijective XCD swizzle (512 blocks % 8 == 0); XCD r owns nt {2r,2r+1}
    const int bid = blockIdx.x;
    const int swz = (bid & 7) * 64 + (bid >> 3);
    const int mt = swz & 31, nt = swz >> 5;       // 32 x 16 tiles
    const int m0 = mt * 256, n0 = nt * 256;

    // per-lane slab-local read offset: T(l) pattern (proven conflict-free, r2)
    //   lb = (l&15)*32 + ((((kg<<1)|((ln>>4)&1)) ^ ((ln>>1)&3)) << 3) elements
    const int lb = (ln & 15) * 32 +
                   (((((kg << 1) | ((ln >> 4) & 1))) ^ ((ln >> 1) & 3)) << 3);
    // A frag base: rows R0 = wm*128 + mf*32 -> element R0*32 = wm*4096 + mf*1024
    const int aRd = wm * 4096 + lb;
    // B frag base: rows wn*64 + nf*32 -> 32768 + wn*2048 + nf*1024
    const int bRd = 32768 + wn * 2048 + lb;

    // staging source = inverse permutation of phi at 16-B chunk granularity:
    // dest chunk g = j*512 + t; slab = g>>6 -> (r5 = slab>>1, c1 = slab&1);
    // fl = (g>>2)&15, w = g&3, q = w ^ ((fl>>1)&3);
    // row = r5*32 + (q&1)*16 + fl  (+128 for j=1), col-chunk = c1*2 + (q>>1).
    const int s_fl = (t >> 2) & 15;
    const int s_q  = (t & 3) ^ ((s_fl >> 1) & 3);
    const int rS = (t >> 6 >> 1) * 32 + (s_q & 1) * 16 + s_fl;
    const int cS = ((t >> 6) & 1) * 2 + (s_q >> 1);
    const bf16_t* sA = Xb + (size_t)(m0 + rS) * IN_F + cS * 8;
    const bf16_t* sB = Wb + (size_t)(n0 + rS) * IN_F + cS * 8;

    floatx16 acc[4][2];
    #pragma unroll
    for (int i = 0; i < 4; ++i) {
        acc[i][0] = (floatx16)(0.0f);
        acc[i][1] = (floatx16)(0.0f);
    }

    // prologue: B-kh0(0), A-kh0(0), B-kh1(0), A-kh1(0); wait first two units
    STG(32768 + 0 * 8192, sB, 0);
    STG(0 * 8192,         sA, 0);
    STG(32768 + 2 * 8192, sB, 32);
    STG(2 * 8192,         sA, 32);
    asm volatile("s_waitcnt vmcnt(4)" ::: "memory");
    BAR;

    for (int kt2 = 0; kt2 < GNT / 2 - 1; ++kt2) {
        const int kt = kt2 * 2;
        KTILE(0, 1, kt + 1, true, true);
        KTILE(1, 0, kt + 2, true, true);
    }
    KTILE(0, 1, GNT - 1, true, true);
    KTILE(1, 0, 0, false, false);

    // C/D layout 32x32x16 (m74/m101): col = lane&31, row = (rg&3)+8*(rg>>2)+4*kg
    const int colb = n0 + wn * 64 + ln;
    const int rowb = m0 + wm * 128 + 4 * kg;
    const float bv0 = bias[colb];
    const float bv1 = bias[colb + 32];
    #pragma unroll
    for (int mf = 0; mf < 4; ++mf) {
        #pragma unroll
        for (int rg = 0; rg < 16; ++rg) {
            const int row = rowb + mf * 32 + (rg & 3) + 8 * (rg >> 2);
            out[(size_t)row * OUT_F + colb]      = acc[mf][0][rg] + bv0;
            out[(size_t)row * OUT_F + colb + 32] = acc[mf][1][rg] + bv1;
        }
    }
}

extern "C" void kernel_launch(void* const* d_in, const int* in_sizes, int n_in,
                              void* d_out, int out_size, void* d_ws, size_t ws_size,
                              hipStream_t stream) {
    const float* x    = (const float*)d_in[0];
    const float* W    = (const float*)d_in[1];
    const float* bias = (const float*)d_in[2];
    const float* lA_  = (const float*)d_in[3];
    const float* lB_  = (const float*)d_in[4];
    float* out = (float*)d_out;

    // workspace layout (~101 MB)
    char* ws = (char*)d_ws;
    bf16_t* Xb  = (bf16_t*)ws;                               // 8192*4096*2 = 67108864
    bf16_t* Wb  = (bf16_t*)(ws + 67108864);                  // 4096*4096*2 = 33554432
    float*  P   = (float*)(ws + 100925440);                  // 256 floats
    float*  Q   = P + 256;
    float*  Sc  = Q + 256;

    pq_kernel  <<<512, 256, 0, stream>>>(lA_, lB_, P, Q);
    ns_kernel  <<<1, 256, 0, stream>>>(P, Q, Sc);
    prep_kernel<<<36864, 256, 0, stream>>>(x, Xb, W, lB_, Sc, lA_, Wb);
    gemm_kernel<<<512, 512, 0, stream>>>(Xb, Wb, bias, out);
}